// Round 1
// baseline (32026.797 us; speedup 1.0000x reference)
//
#include <hip/hip_runtime.h>

namespace {

constexpr int Bb = 32, Tt = 64, Dd = 1024, Hh = 1024, Vv = 32000, MX = 100;
constexpr long TBV = (long)Tt * Bb * Vv;

typedef __bf16 bf16x8 __attribute__((ext_vector_type(8)));
typedef float floatx4 __attribute__((ext_vector_type(4)));

__device__ __forceinline__ float sigf(float x) { return 1.0f / (1.0f + expf(-x)); }

__device__ __forceinline__ __bf16 f2bf(float x) {
  unsigned u = __builtin_bit_cast(unsigned, x);
  unsigned short r = (unsigned short)((u + 0x7FFFu + ((u >> 16) & 1u)) >> 16);
  return __builtin_bit_cast(__bf16, r);
}

__global__ __launch_bounds__(64) void init_tok(int* __restrict__ tok) {
  int i = threadIdx.x;
  if (i < Bb) tok[i] = 1;  // GO token
}

// X[row, k] = bf16(Wo[tgt[b*T+t], k]) with row = t*32+b (time-major)
__global__ __launch_bounds__(256) void gather_cast_x(
    const int* __restrict__ tgt, const float* __restrict__ Wo,
    __bf16* __restrict__ X) {
  int i = blockIdx.x * 256 + threadIdx.x;  // 262144 chunks of 8
  int row = i >> 7, ko = (i & 127) * 8;
  int tt = row >> 5, b = row & 31;
  const float* src = Wo + (long)tgt[b * Tt + tt] * Dd + ko;
  float4 v0 = *(const float4*)src, v1 = *(const float4*)(src + 4);
  bf16x8 w;
  w[0] = f2bf(v0.x); w[1] = f2bf(v0.y); w[2] = f2bf(v0.z); w[3] = f2bf(v0.w);
  w[4] = f2bf(v1.x); w[5] = f2bf(v1.y); w[6] = f2bf(v1.z); w[7] = f2bf(v1.w);
  *(bf16x8*)(X + (long)row * Dd + ko) = w;
}

// in: fp32 [K,N] row-major  ->  out: bf16 [N,K] row-major.  grid(N/64, K/64)
__global__ __launch_bounds__(256) void transpose_cast(
    const float* __restrict__ in, __bf16* __restrict__ out, int K, int N) {
  __shared__ __bf16 tile[64][72];  // [n][k]
  int k0 = blockIdx.y * 64, n0 = blockIdx.x * 64;
  int t = threadIdx.x;
#pragma unroll
  for (int cc = 0; cc < 4; cc++) {
    int cid = t + cc * 256;  // 1024 float4 chunks
    int kk = cid >> 4, nn = (cid & 15) * 4;
    float4 v = *(const float4*)(in + (long)(k0 + kk) * N + n0 + nn);
    tile[nn + 0][kk] = f2bf(v.x);
    tile[nn + 1][kk] = f2bf(v.y);
    tile[nn + 2][kk] = f2bf(v.z);
    tile[nn + 3][kk] = f2bf(v.w);
  }
  __syncthreads();
#pragma unroll
  for (int cc = 0; cc < 2; cc++) {
    int cid = t + cc * 256;  // 512 bf16x8 chunks
    int nn = cid >> 3, kk = (cid & 7) * 8;
    bf16x8 w;
#pragma unroll
    for (int j = 0; j < 8; j++) w[j] = tile[nn][kk + j];
    *(bf16x8*)(out + (long)(n0 + nn) * K + k0 + kk) = w;
  }
}

// C[M,N] fp32 = A[M,K]bf16 @ BT[N,K]bf16^T (+bias). 128x128 tile, 4 waves.
__global__ __launch_bounds__(256) void gemm_mfma(
    const __bf16* __restrict__ A, const __bf16* __restrict__ BT,
    float* __restrict__ C, int ldc, int K, const float* __restrict__ bias) {
  __shared__ __bf16 As[128 * 40];
  __shared__ __bf16 Bs[128 * 40];
  const int t = threadIdx.x;
  const int lane = t & 63, wave = t >> 6;
  const int m0 = blockIdx.y * 128, n0 = blockIdx.x * 128;
  const int wm = (wave >> 1) * 64, wn = (wave & 1) * 64;
  const int fr = lane & 15;        // frag row (m or n within 16-tile)
  const int fk = (lane >> 4) * 8;  // frag k offset
  floatx4 acc[4][4] = {};
  for (int k0 = 0; k0 < K; k0 += 32) {
#pragma unroll
    for (int cc = 0; cc < 2; cc++) {
      int cid = t + cc * 256;
      int row = cid >> 2, ko = (cid & 3) * 8;
      *(bf16x8*)(As + row * 40 + ko) =
          *(const bf16x8*)(A + (long)(m0 + row) * K + k0 + ko);
      *(bf16x8*)(Bs + row * 40 + ko) =
          *(const bf16x8*)(BT + (long)(n0 + row) * K + k0 + ko);
    }
    __syncthreads();
    bf16x8 af[4], bg[4];
#pragma unroll
    for (int i = 0; i < 4; i++) {
      af[i] = *(const bf16x8*)(As + (wm + i * 16 + fr) * 40 + fk);
      bg[i] = *(const bf16x8*)(Bs + (wn + i * 16 + fr) * 40 + fk);
    }
#pragma unroll
    for (int i = 0; i < 4; i++)
#pragma unroll
      for (int j = 0; j < 4; j++)
        acc[i][j] = __builtin_amdgcn_mfma_f32_16x16x32_bf16(af[i], bg[j],
                                                            acc[i][j], 0, 0, 0);
    __syncthreads();
  }
  const int cr = (lane >> 4) * 4;
#pragma unroll
  for (int i = 0; i < 4; i++)
#pragma unroll
    for (int j = 0; j < 4; j++) {
      int n = n0 + wn + j * 16 + fr;
      float bv = bias ? bias[n] : 0.f;
#pragma unroll
      for (int r = 0; r < 4; r++) {
        int m = m0 + wm + i * 16 + cr + r;
        C[(long)m * ldc + n] = acc[i][j][r] + bv;
      }
    }
}

// ---------- software grid barrier (fresh counter slot per use) ----------
__device__ __forceinline__ void gridbar(int* __restrict__ ctr, int nblk) {
  __syncthreads();
  if (threadIdx.x == 0) {
    __threadfence();  // release: publish this block's writes (agent scope)
    __hip_atomic_fetch_add(ctr, 1, __ATOMIC_RELEASE, __HIP_MEMORY_SCOPE_AGENT);
    while (__hip_atomic_load(ctr, __ATOMIC_RELAXED, __HIP_MEMORY_SCOPE_AGENT) <
           nblk)
      __builtin_amdgcn_s_sleep(2);
    __threadfence();  // acquire: invalidate stale cached lines
  }
  __syncthreads();
}

// ---------- shared fp32 32x64 GEMM tile body ----------
// C[32 x 64] tile: per-thread acc[2][4] for rows mg..mg+1, cols ng..ng+3.
// Arow: this thread's A staging row pointer (row lm = t&31, at k=0).
// Bt:   this thread's B staging pointer (row kr = t>>3, col cb = (t&7)*8).
// Accumulation is ascending-k fp32 FMA per output element (bit-identical to
// the previous per-kernel versions).
__device__ __forceinline__ void gemm_tile(float* __restrict__ Asm /*32*34*/,
                                          float* __restrict__ Bsm /*32*64*/,
                                          const float* __restrict__ Arow,
                                          const float* __restrict__ Bt,
                                          long ldb, int niter, int t,
                                          float acc[2][4]) {
  const int kq = (t >> 5) * 4, lm = t & 31;
  const int kr = t >> 3, cb = (t & 7) * 8;
  const int mg = (t >> 4) * 2, ng = (t & 15) * 4;
  float4 av = *(const float4*)(Arow + kq);
  float4 b0 = *(const float4*)Bt;
  float4 b1 = *(const float4*)(Bt + 4);
  for (int it = 0; it < niter; ++it) {
    Asm[(kq + 0) * 34 + lm] = av.x;
    Asm[(kq + 1) * 34 + lm] = av.y;
    Asm[(kq + 2) * 34 + lm] = av.z;
    Asm[(kq + 3) * 34 + lm] = av.w;
    *(float4*)(&Bsm[kr * 64 + cb]) = b0;
    *(float4*)(&Bsm[kr * 64 + cb + 4]) = b1;
    __syncthreads();
    if (it + 1 < niter) {  // prefetch next tile into regs (hides L2/L3 latency)
      Arow += 32;
      Bt += 32 * ldb;
      av = *(const float4*)(Arow + kq);
      b0 = *(const float4*)Bt;
      b1 = *(const float4*)(Bt + 4);
    }
#pragma unroll
    for (int k = 0; k < 32; ++k) {
      float2 a = *(const float2*)(&Asm[k * 34 + mg]);    // ds_read_b64
      float4 bv = *(const float4*)(&Bsm[k * 64 + ng]);   // ds_read_b128
      acc[0][0] = fmaf(a.x, bv.x, acc[0][0]);
      acc[0][1] = fmaf(a.x, bv.y, acc[0][1]);
      acc[0][2] = fmaf(a.x, bv.z, acc[0][2]);
      acc[0][3] = fmaf(a.x, bv.w, acc[0][3]);
      acc[1][0] = fmaf(a.y, bv.x, acc[1][0]);
      acc[1][1] = fmaf(a.y, bv.y, acc[1][1]);
      acc[1][2] = fmaf(a.y, bv.z, acc[1][2]);
      acc[1][3] = fmaf(a.y, bv.w, acc[1][3]);
    }
    __syncthreads();
  }
}

// ---------- phase A: all 64 teacher-forced steps in one kernel ----------
// grid 256 blocks x 256 thr; block b: n0=(b&63)*64, ks=b>>6 in [0,4).
// per step: zp[ks] = h[:, ks*256..+256] @ Wh[...]  | bar | gates | bar
__global__ __launch_bounds__(256, 2) void phaseA_all(
    const float* __restrict__ XZ, const float* __restrict__ Wh,
    float* __restrict__ zp, float* __restrict__ h, float* __restrict__ c,
    __bf16* __restrict__ hsb, int* __restrict__ barc) {
  __shared__ float Asm[32 * 34];
  __shared__ float Bsm[32 * 64];
  const int b = blockIdx.x, t = threadIdx.x;
  const int n0 = (b & 63) * 64, ks = b >> 6;
  const int lm = t & 31, kr = t >> 3, cb = (t & 7) * 8;
  const int mg = (t >> 4) * 2, ng = (t & 15) * 4;
  for (int step = 0; step < Tt; ++step) {
    {
      const float* Arow = h + (long)lm * Hh + ks * 256;
      const float* Bt = Wh + (long)(ks * 256 + kr) * 4096 + n0 + cb;
      float acc[2][4] = {};
      gemm_tile(Asm, Bsm, Arow, Bt, 4096, 8, t, acc);
#pragma unroll
      for (int i = 0; i < 2; i++) {
        floatx4 v = {acc[i][0], acc[i][1], acc[i][2], acc[i][3]};
        *(floatx4*)(&zp[((long)ks * 32 + mg + i) * 4096 + n0 + ng]) = v;
      }
    }
    gridbar(barc + step * 2, 256);
    if (t < 128) {  // gates: 256 blocks x 128 elems = 32768
      int idx = b * 128 + t;
      int m = idx >> 10, n = idx & 1023;
      long o = (long)m * 4096 + n;
      const float* base = XZ + (long)step * 131072;
      float z[4];
#pragma unroll
      for (int g = 0; g < 4; g++) {
        float v = base[o + g * 1024];
#pragma unroll
        for (int kss = 0; kss < 4; kss++)
          v += zp[(long)kss * 131072 + o + g * 1024];
        z[g] = v;
      }
      float cn = sigf(z[1] + 1.0f) * c[idx] + sigf(z[0]) * tanhf(z[2]);
      float hn = sigf(z[3]) * tanhf(cn);
      c[idx] = cn;
      h[idx] = hn;
      hsb[(long)step * 32768 + idx] = f2bf(hn);
    }
    gridbar(barc + step * 2 + 1, 256);
  }
}

// ---------- phase B: all 100 greedy steps in one kernel ----------
// grid 512 blocks x 256 thr.
// per step: zp (512 blk) | bar | gates (512 blk x 64) | bar |
//           lg partial argmax (500 blk) | bar | final argmax (blk 0) | bar
__global__ __launch_bounds__(256, 2) void phaseB_all(
    const float* __restrict__ Wo, const float* __restrict__ Wx,
    const float* __restrict__ Wh, const float* __restrict__ bias,
    const float* __restrict__ Wp, float* __restrict__ h, float* __restrict__ c,
    float* __restrict__ zp, float* __restrict__ pv, int* __restrict__ pi,
    int* __restrict__ tok, float* __restrict__ best, int* __restrict__ barc) {
  __shared__ float Asm[32 * 34];
  __shared__ float Bsm[32 * 64];
  __shared__ float rv[32 * 16];
  __shared__ int ri[32 * 16];
  const int b = blockIdx.x, t = threadIdx.x;
  const int lm = t & 31, kr = t >> 3, cb = (t & 7) * 8;
  const int mg = (t >> 4) * 2, ng = (t & 15) * 4;
  for (int s = 0; s < MX; ++s) {
    int* bs = barc + s * 4;
    {  // ph1: zp partials over combined K=2048 (x@Wx then h@Wh)
      const int n0 = (b & 63) * 64, ks = b >> 6;
      const float* Arow;
      const float* Bt;
      if (ks < 4) {
        int kbase = ks * 256;
        Arow = Wo + (long)tok[lm] * Dd + kbase;
        Bt = Wx + (long)(kbase + kr) * 4096 + n0 + cb;
      } else {
        int kbase = (ks - 4) * 256;
        Arow = h + (long)lm * Hh + kbase;
        Bt = Wh + (long)(kbase + kr) * 4096 + n0 + cb;
      }
      float acc[2][4] = {};
      gemm_tile(Asm, Bsm, Arow, Bt, 4096, 8, t, acc);
#pragma unroll
      for (int i = 0; i < 2; i++) {
        floatx4 v = {acc[i][0], acc[i][1], acc[i][2], acc[i][3]};
        *(floatx4*)(&zp[((long)ks * 32 + mg + i) * 4096 + n0 + ng]) = v;
      }
    }
    gridbar(bs + 0, 512);
    if (t < 64) {  // ph2: gates, 512 blocks x 64 elems = 32768
      int idx = b * 64 + t;
      int m = idx >> 10, n = idx & 1023;
      long o = (long)m * 4096 + n;
      float z[4];
#pragma unroll
      for (int g = 0; g < 4; g++) {
        float v = bias[g * 1024 + n];
#pragma unroll
        for (int kss = 0; kss < 8; kss++)
          v += zp[(long)kss * 131072 + o + g * 1024];
        z[g] = v;
      }
      float cn = sigf(z[1] + 1.0f) * c[idx] + sigf(z[0]) * tanhf(z[2]);
      float hn = sigf(z[3]) * tanhf(cn);
      c[idx] = cn;
      h[idx] = hn;
    }
    gridbar(bs + 1, 512);
    if (b < 500) {  // ph3: lg = h @ Wp for 64-col tile, fused tile-argmax
      const int n0 = b * 64;
      const float* Arow = h + (long)lm * Hh;
      const float* Bt = Wp + (long)kr * Vv + n0 + cb;
      float acc[2][4] = {};
      gemm_tile(Asm, Bsm, Arow, Bt, Vv, 32, t, acc);
      const int cbase = n0 + ng;
#pragma unroll
      for (int i = 0; i < 2; i++) {
        float bvv = acc[i][0];
        int bii = cbase;
#pragma unroll
        for (int j = 1; j < 4; j++)
          if (acc[i][j] > bvv) { bvv = acc[i][j]; bii = cbase + j; }
        rv[(mg + i) * 16 + (t & 15)] = bvv;
        ri[(mg + i) * 16 + (t & 15)] = bii;
      }
      __syncthreads();
      if (t < 32) {
        float bvv = -3.402823466e38f;
        int bii = 0x7fffffff;
        for (int j = 0; j < 16; j++) {
          float v = rv[t * 16 + j];
          int id = ri[t * 16 + j];
          if (v > bvv || (v == bvv && id < bii)) { bvv = v; bii = id; }
        }
        pv[t * 500 + b] = bvv;
        pi[t * 500 + b] = bii;
      }
    }
    gridbar(bs + 2, 512);
    if (b == 0) {  // ph4: final argmax over 500 tiles (first-wins ties)
      int r = t >> 3, j = t & 7;
      float bvv = -3.402823466e38f;
      int bii = 0x7fffffff;
      for (int e = j; e < 500; e += 8) {
        float v = pv[r * 500 + e];
        int id = pi[r * 500 + e];
        if (v > bvv || (v == bvv && id < bii)) { bvv = v; bii = id; }
      }
      rv[r * 8 + j] = bvv;
      ri[r * 8 + j] = bii;
      __syncthreads();
      if (t < 32) {
        float fv = rv[t * 8];
        int fi = ri[t * 8];
        for (int j2 = 1; j2 < 8; j2++) {
          float v = rv[t * 8 + j2];
          int id = ri[t * 8 + j2];
          if (v > fv || (v == fv && id < fi)) { fv = v; fi = id; }
        }
        tok[t] = fi;
        best[s * Bb + t] = (float)fi;
      }
    }
    gridbar(bs + 3, 512);
  }
}

// online two-pass softmax. grid(T*B)
__global__ __launch_bounds__(256) void softmax_k(
    const float* __restrict__ lgts, float* __restrict__ pr) {
  __shared__ float rm[256], rs[256];
  const int r = blockIdx.x, t = threadIdx.x;
  const float* x = lgts + (long)r * Vv;
  float* p = pr + (long)r * Vv;
  float mx = -3.402823466e38f, sm = 0.f;
  for (int i = t; i < Vv; i += 256) {
    float v = x[i];
    if (v > mx) { sm = sm * __expf(mx - v) + 1.f; mx = v; }
    else sm += __expf(v - mx);
  }
  rm[t] = mx; rs[t] = sm;
  __syncthreads();
  for (int s = 128; s > 0; s >>= 1) {
    if (t < s) {
      float m2 = rm[t + s], s2 = rs[t + s];
      float M = fmaxf(rm[t], m2);
      rs[t] = rs[t] * __expf(rm[t] - M) + s2 * __expf(m2 - M);
      rm[t] = M;
    }
    __syncthreads();
  }
  float M = rm[0], inv = 1.f / rs[0];
  for (int i = t; i < Vv; i += 256) p[i] = __expf(x[i] - M) * inv;
}

}  // namespace

extern "C" void kernel_launch(void* const* d_in, const int* in_sizes, int n_in,
                              void* d_out, int out_size, void* d_ws, size_t ws_size,
                              hipStream_t stream) {
  const int* tgt  = (const int*)d_in[0];
  const float* Wo = (const float*)d_in[1];
  const float* Wx = (const float*)d_in[2];
  const float* Wh = (const float*)d_in[3];
  const float* bb = (const float*)d_in[4];
  const float* Wp = (const float*)d_in[5];

  float* out = (float*)d_out;
  float* logits = out;          // [T*B, V]
  float* probs = out + TBV;     // [T*B, V]
  float* best = out + 2 * TBV;  // [MX, B] as float

  // big scratch in the probs region (softmax runs last, overwrites)
  float* XZ = probs;                                 // [2048,4096] fp32
  __bf16* Xtm   = (__bf16*)(probs + 8388608);        // [2048,1024] bf16
  __bf16* hs_bf = (__bf16*)(probs + 8388608 + 1048576);
  __bf16* WxT   = (__bf16*)(probs + 8388608 + 2 * 1048576);   // [4096,1024]
  __bf16* WpT   = (__bf16*)(probs + 8388608 + 4 * 1048576);   // [32000,1024]

  float* ws = (float*)d_ws;
  float* h = ws;                           // [32,1024]
  float* c = h + Bb * Hh;                  // [32,1024]
  float* zp = c + Bb * Hh;                 // [8][32][4096]
  float* pv = zp + 8 * Bb * 4 * Hh;        // [32][500]
  int* pi = (int*)(pv + 32 * 500);         // [32][500]
  int* tok = pi + 32 * 500;                // [32]
  int* barc = tok + 32;                    // [1024] barrier counters

  // ---- one-time casts / gathers ----
  gather_cast_x<<<1024, 256, 0, stream>>>(tgt, Wo, Xtm);
  transpose_cast<<<dim3(64, 16), 256, 0, stream>>>(Wx, WxT, Dd, 4 * Hh);
  transpose_cast<<<dim3(500, 16), 256, 0, stream>>>(Wp, WpT, Hh, Vv);
  hipMemsetAsync(barc, 0, 1024 * sizeof(int), stream);

  // ---- phase A: teacher-forced (single persistent kernel) ----
  hipMemsetAsync(h, 0, 2 * Bb * Hh * sizeof(float), stream);  // h, c = 0
  gemm_mfma<<<dim3(32, 16), 256, 0, stream>>>(Xtm, WxT, XZ, 4 * Hh, Dd, bb);
  phaseA_all<<<256, 256, 0, stream>>>(XZ, Wh, zp, h, c, hs_bf, barc);
  // logits = hs @ Wp   (bf16 MFMA)
  gemm_mfma<<<dim3(250, 16), 256, 0, stream>>>(hs_bf, WpT, logits, Vv, Hh,
                                               nullptr);

  // ---- phase B: greedy decode (single persistent kernel, fp32) ----
  hipMemsetAsync(h, 0, 2 * Bb * Hh * sizeof(float), stream);
  init_tok<<<1, 64, 0, stream>>>(tok);
  phaseB_all<<<512, 256, 0, stream>>>(Wo, Wx, Wh, bb, Wp, h, c, zp, pv, pi,
                                      tok, best, barc + 128);

  // ---- softmax last (scratch region is dead now) ----
  softmax_k<<<Tt * Bb, 256, 0, stream>>>(logits, probs);
}